// Round 8
// baseline (307.450 us; speedup 1.0000x reference)
//
#include <hip/hip_runtime.h>
#include <math.h>

#define NB    2048
#define NSEG  20
#define MAXIT 48
// LDS chunk layout: one 32-k chunk = 4 octet-blocks of BLKS shorts.
// BLKS = 128 data shorts (16 cols x 8 k) + 8 pad shorts = 136.
// cols 0..7 = bf16-hi of elems 0..7, cols 8..15 = bf16-lo of elems 0..7.
// Bank math: BLKS*2B = 272B = 68 dwords == 4 (mod 32); chunk stride 544*2/4 = 272 == 16 (mod 32).
#define CH    544
#define BLKS  136

typedef __attribute__((ext_vector_type(8))) short bf8_t;
typedef __attribute__((ext_vector_type(4))) float f32x4;

#define cA21 ((float)0.161)
#define cA31 ((float)-0.008480655492356989)
#define cA32 ((float)0.335480655492357)
#define cA41 ((float)2.8971530571054935)
#define cA42 ((float)-6.359448489975075)
#define cA43 ((float)4.3622954328695815)
#define cA51 ((float)5.325864828439257)
#define cA52 ((float)-11.748883564062828)
#define cA53 ((float)7.4955393428898365)
#define cA54 ((float)-0.09249506636175525)
#define cA61 ((float)5.86145544294642)
#define cA62 ((float)-12.92096931784711)
#define cA63 ((float)8.159367898576159)
#define cA64 ((float)-0.071584973281401)
#define cA65 ((float)-0.028269050394068383)
#define cB1  ((float)0.09646076681806523)
#define cB2  ((float)0.01)
#define cB3  ((float)0.4798896504144996)
#define cB4  ((float)1.379008574103742)
#define cB5  ((float)-3.290069515436081)
#define cB6  ((float)2.324710524099774)
#define cE1  ((float)-0.001780011052225777)
#define cE2  ((float)-0.0008164344596567469)
#define cE3  ((float)0.007880878010261995)
#define cE4  ((float)-0.1447110071732629)
#define cE5  ((float)0.5823571654525552)
#define cE6  ((float)-0.45808210592918697)
#define cE7  ((float)0.015151515151515152)

__device__ __forceinline__ void split2(float x, short &hi, short &lo) {
    // x ~= bf16(hi) + bf16(lo), truncation-based (x - hi is exact in fp32)
    unsigned u = __float_as_uint(x);
    hi = (short)(u >> 16);
    float r = x - __uint_as_float(u & 0xFFFF0000u);
    lo = (short)(__float_as_uint(r) >> 16);
}

__device__ __forceinline__ float softplus_f(float x) {
    float t = exp2f(-fabsf(x) * 1.442695040888963f);
    return fmaxf(x, 0.0f) + log2f(1.0f + t) * 0.6931471805599453f;
}

__device__ __forceinline__ unsigned pk(short a, short b) {
    return ((unsigned)(unsigned short)a) | (((unsigned)(unsigned short)b) << 16);
}

// x + x[lane^8] within each 16-lane row: DPP row_ror:8 (0x128).  Pure VALU.
// NOTE: apply BEFORE any esel-dependent register select (round-4 lesson).
__device__ __forceinline__ float fold8(float x) {
    int r = __builtin_amdgcn_update_dpp(__float_as_int(x), __float_as_int(x),
                                        0x128, 0xF, 0xF, false);
    return x + __int_as_float(r);
}

// 512 threads = 8 waves; block processes 8 elements in lockstep.
// z-space formulation: track zy = W1*y + b1 and u_i = W1*k_i instead of
// staging args.  arg combos become per-lane z-space FMAs (no L1 gemm, no
// arg LDS redistribution): z1_st = zy + h*sum_i A_i u_i;  h1 = sp(z1).
// u_i = M*h2_i + c with M = W1*W3 (128x128, computed per-block at preload)
// and c = W1*b3 (init gemm).  Per eval: [combo+sp -> h1B] bar [W2 gemm ->
// h2B] bar [M-gemm -> u (all waves, z-layout!), W3-gemm -> k (waves 0-3)].
// 2 gemm phases / 2 barriers per eval (was 3).  k-path (W3, b3) numerically
// unchanged -> step controller noise unchanged.  FSAL: u1<-u7, zy<-zy5.
// Frag-layout (16x16x32 bf16): A[m=lane&15][k=32c+8*quad+jj]; B[k][n=lane&15];
// C/D: col=lane&15, row=4*quad+reg  (m89-verified).
__global__ __launch_bounds__(512)
void ode_kernel(const float* __restrict__ history,
                const float* __restrict__ W1, const float* __restrict__ b1,
                const float* __restrict__ W2, const float* __restrict__ b2,
                const float* __restrict__ W3, const float* __restrict__ b3,
                float* __restrict__ out)
{
    __shared__ alignas(16) short h1B[4 * CH];
    __shared__ alignas(16) short h2B[4 * CH];
    __shared__ float rrP[32];   // [wave<4][elem] error-norm partials

    const int tid  = threadIdx.x;
    const int wave = tid >> 6, lane = tid & 63;
    const int quad = lane >> 4, col = lane & 15;
    const int jb   = 16 * wave + 4 * quad;       // D-row base of this lane
    const int esel = col >> 3;
    const int e    = col & 7;
    const int j0   = jb + 2 * esel;              // z-dim base (0..127); y-dim for waves<4
    const size_t elemIdx = (size_t)(blockIdx.x * 8 + e);
    // shared B-layout index for (rows j0,j0+1, col e) hi; +64 = lo col group
    const int zi   = (j0 >> 5) * CH + ((j0 >> 3) & 3) * BLKS + e * 8 + (j0 & 7);
    const int boff = quad * BLKS + col * 8;

    // ---- W2 frags (all waves, rows 16w+col) ----
    bf8_t A2h[4], A2l[4];
#pragma unroll
    for (int c = 0; c < 4; ++c) {
        const float* p = W2 + (size_t)(16 * wave + col) * 128 + 32 * c + 8 * quad;
        bf8_t h, l;
#pragma unroll
        for (int j = 0; j < 8; ++j) { short hs, ls; split2(p[j], hs, ls); h[j] = hs; l[j] = ls; }
        A2h[c] = h; A2l[c] = l;
    }
    // ---- W3 frags (waves 0-3; zero elsewhere) + b3 pair ----
    bf8_t A3h[4], A3l[4];
    float b3v0 = 0.f, b3v1 = 0.f;
    if (wave < 4) {
#pragma unroll
        for (int c = 0; c < 4; ++c) {
            const float* p = W3 + (size_t)(16 * wave + col) * 128 + 32 * c + 8 * quad;
            bf8_t h, l;
#pragma unroll
            for (int j = 0; j < 8; ++j) { short hs, ls; split2(p[j], hs, ls); h[j] = hs; l[j] = ls; }
            A3h[c] = h; A3l[c] = l;
        }
        b3v0 = b3[j0]; b3v1 = b3[j0 + 1];
    } else {
        bf8_t z = {0, 0, 0, 0, 0, 0, 0, 0};
#pragma unroll
        for (int c = 0; c < 4; ++c) { A3h[c] = z; A3l[c] = z; }
    }
    const f32x4 b2f = *(const f32x4*)(b2 + jb);
    const float b1v0 = b1[j0], b1v1 = b1[j0 + 1];

    // ---- M = W1*W3 frags (row 16w+col, all 8 waves): 32 entries/lane ----
    bf8_t Mh[4], Ml[4];
    {
        float accM[4][8];
#pragma unroll
        for (int cc = 0; cc < 4; ++cc)
#pragma unroll
            for (int j = 0; j < 8; ++j) accM[cc][j] = 0.f;
        const float* w1r = W1 + (size_t)(16 * wave + col) * 64;
#pragma unroll 2
        for (int d = 0; d < 64; ++d) {
            float wv = w1r[d];
            const float* w3r = W3 + (size_t)d * 128 + 8 * quad;
#pragma unroll
            for (int cc = 0; cc < 4; ++cc) {
                f32x4 va = *(const f32x4*)(w3r + 32 * cc);
                f32x4 vb = *(const f32x4*)(w3r + 32 * cc + 4);
#pragma unroll
                for (int j = 0; j < 4; ++j) {
                    accM[cc][j]     = fmaf(wv, va[j], accM[cc][j]);
                    accM[cc][4 + j] = fmaf(wv, vb[j], accM[cc][4 + j]);
                }
            }
        }
#pragma unroll
        for (int cc = 0; cc < 4; ++cc) {
            bf8_t hh, ll;
#pragma unroll
            for (int j = 0; j < 8; ++j) { short hs, ls; split2(accM[cc][j], hs, ls); hh[j] = hs; ll[j] = ls; }
            Mh[cc] = hh; Ml[cc] = ll;
        }
    }

    // returns per-reg sum of the two accumulator chains (pre-fold)
    auto gemm = [&](const bf8_t* Ah, const bf8_t* Al, const short* Bc, int nch) -> f32x4 {
        f32x4 a0 = {0.f, 0.f, 0.f, 0.f}, a1 = a0;
#pragma unroll
        for (int c = 0; c < nch; ++c) {
            bf8_t b = *(const bf8_t*)(Bc + c * CH + boff);
            a0 = __builtin_amdgcn_mfma_f32_16x16x32_bf16(Ah[c], b, a0, 0, 0, 0);
            a1 = __builtin_amdgcn_mfma_f32_16x16x32_bf16(Al[c], b, a1, 0, 0, 0);
        }
        f32x4 s;
#pragma unroll
        for (int r = 0; r < 4; ++r) s[r] = a0[r] + a1[r];
        return s;
    };

    // ---- init: zy = W1*y0 + b1 and c = W1*b3 via one gemm phase ----
    float zy0, zy1, cc0, cc1;
    float ys0 = 0.f, ys1 = 0.f;
    {
        bf8_t W1h[2], W1l[2];
#pragma unroll
        for (int c = 0; c < 2; ++c) {
            const float* p = W1 + (size_t)(16 * wave + col) * 64 + 32 * c + 8 * quad;
            bf8_t h, l;
#pragma unroll
            for (int j = 0; j < 8; ++j) { short hs, ls; split2(p[j], hs, ls); h[j] = hs; l[j] = ls; }
            W1h[c] = h; W1l[c] = l;
        }
        if (wave < 4) {   // stage y0 into h1B chunks 0-1, b3 into h2B chunks 0-1
            float2 yy = *(const float2*)(history + (elemIdx * 15 + 14) * 64 + j0);
            ys0 = yy.x; ys1 = yy.y;
            short ha, la, hb, lb;
            split2(ys0, ha, la); split2(ys1, hb, lb);
            *(unsigned*)(h1B + zi)      = pk(ha, hb);
            *(unsigned*)(h1B + zi + 64) = pk(la, lb);
            split2(b3v0, ha, la); split2(b3v1, hb, lb);
            *(unsigned*)(h2B + zi)      = pk(ha, hb);
            *(unsigned*)(h2B + zi + 64) = pk(la, lb);
        }
        __syncthreads();
        f32x4 sz = gemm(W1h, W1l, h1B, 2);
        f32x4 sc = gemm(W1h, W1l, h2B, 2);
        float f0 = fold8(sz[0]), f1 = fold8(sz[1]), f2 = fold8(sz[2]), f3 = fold8(sz[3]);
        zy0 = (esel ? f2 : f0) + b1v0;
        zy1 = (esel ? f3 : f1) + b1v1;
        float g0 = fold8(sc[0]), g1 = fold8(sc[1]), g2 = fold8(sc[2]), g3 = fold8(sc[3]);
        cc0 = esel ? g2 : g0;
        cc1 = esel ? g3 : g1;
        __syncthreads();   // scratch reads done before first h1B overwrite
    }

    // P1 epilogue: fold ALL regs first, select after (round-4 lesson)
    auto epi = [&](f32x4 s, f32x4 bias, short* Bn) {
        float t0 = fold8(s[0]) + bias[0];
        float t1 = fold8(s[1]) + bias[1];
        float t2 = fold8(s[2]) + bias[2];
        float t3 = fold8(s[3]) + bias[3];
        float x0 = esel ? t2 : t0;
        float x1 = esel ? t3 : t1;
        float p0 = softplus_f(x0), p1 = softplus_f(x1);
        short h0s, l0s, h1s, l1s;
        split2(p0, h0s, l0s);
        split2(p1, h1s, l1s);
        *(unsigned*)(Bn + zi)      = pk(h0s, h1s);
        *(unsigned*)(Bn + zi + 64) = pk(l0s, l1s);
    };

    // one eval given z1 values: sp -> h1B; bar; W2 -> h2B; bar; M+W3 (shared
    // B reads) -> u (all waves, +c) and k (waves 0-3, +b3).
    auto do_eval = [&](float za, float zb, float &ua, float &ub, float &ka, float &kb) {
        float p0 = softplus_f(za), p1 = softplus_f(zb);
        short h0s, l0s, h1s, l1s;
        split2(p0, h0s, l0s);
        split2(p1, h1s, l1s);
        *(unsigned*)(h1B + zi)      = pk(h0s, h1s);
        *(unsigned*)(h1B + zi + 64) = pk(l0s, l1s);
        __syncthreads();
        f32x4 s2 = gemm(A2h, A2l, h1B, 4);
        epi(s2, b2f, h2B);
        __syncthreads();
        f32x4 zz = {0.f, 0.f, 0.f, 0.f};
        f32x4 m0 = zz, m1 = zz, w0 = zz, w1 = zz;
#pragma unroll
        for (int c = 0; c < 4; ++c) {
            bf8_t b = *(const bf8_t*)(h2B + c * CH + boff);
            m0 = __builtin_amdgcn_mfma_f32_16x16x32_bf16(Mh[c],  b, m0, 0, 0, 0);
            m1 = __builtin_amdgcn_mfma_f32_16x16x32_bf16(Ml[c],  b, m1, 0, 0, 0);
            w0 = __builtin_amdgcn_mfma_f32_16x16x32_bf16(A3h[c], b, w0, 0, 0, 0);
            w1 = __builtin_amdgcn_mfma_f32_16x16x32_bf16(A3l[c], b, w1, 0, 0, 0);
        }
        float f0 = fold8(m0[0] + m1[0]);
        float f1 = fold8(m0[1] + m1[1]);
        float f2 = fold8(m0[2] + m1[2]);
        float f3 = fold8(m0[3] + m1[3]);
        ua = (esel ? f2 : f0) + cc0;
        ub = (esel ? f3 : f1) + cc1;
        float g0 = fold8(w0[0] + w1[0]);
        float g1 = fold8(w0[1] + w1[1]);
        float g2 = fold8(w0[2] + w1[2]);
        float g3 = fold8(w0[3] + w1[3]);
        ka = (esel ? g2 : g0) + b3v0;
        kb = (esel ? g3 : g1) + b3v1;
    };

    // ---- state: z-space (all waves) + y-space (waves 0-3) ----
    float dt = 0.1f;
    float u1a, u1b, u2a, u2b, u3a, u3b, u4a, u4b, u5a, u5b, u6a, u6b;
    float k1a = 0.f, k1b = 0.f, k2a, k2b, k3a, k3b, k4a, k4b, k5a, k5b, k6a, k6b;

    // initial k1 = f(y0): z1 = zy  (FSAL thereafter)
    do_eval(zy0, zy1, u1a, u1b, k1a, k1b);

#pragma unroll 1
    for (int seg = 1; seg <= NSEG; ++seg) {
        const float t1 = (float)seg;
        float t = t1 - 1.0f;
        bool done = false;

#pragma unroll 1
        for (int it = 0; it < MAXIT; ++it) {
            const float dt_c = fminf(dt, t1 - t);
            const float h = dt_c;
            float y50 = 0.f, y51 = 0.f, k7a = 0.f, k7b = 0.f;
            float u7a = 0.f, u7b = 0.f, zy5a = 0.f, zy5b = 0.f;

#pragma unroll 1
            for (int st = 2; st <= 7; ++st) {
                float sa, sb;
                switch (st) {
                    case 2: sa = cA21 * u1a;
                            sb = cA21 * u1b; break;
                    case 3: sa = fmaf(cA31, u1a, cA32 * u2a);
                            sb = fmaf(cA31, u1b, cA32 * u2b); break;
                    case 4: sa = fmaf(cA41, u1a, fmaf(cA42, u2a, cA43 * u3a));
                            sb = fmaf(cA41, u1b, fmaf(cA42, u2b, cA43 * u3b)); break;
                    case 5: sa = fmaf(cA51, u1a, fmaf(cA52, u2a, fmaf(cA53, u3a, cA54 * u4a)));
                            sb = fmaf(cA51, u1b, fmaf(cA52, u2b, fmaf(cA53, u3b, cA54 * u4b))); break;
                    case 6: sa = fmaf(cA61, u1a, fmaf(cA62, u2a, fmaf(cA63, u3a, fmaf(cA64, u4a, cA65 * u5a))));
                            sb = fmaf(cA61, u1b, fmaf(cA62, u2b, fmaf(cA63, u3b, fmaf(cA64, u4b, cA65 * u5b)))); break;
                    default: sa = fmaf(cB1, u1a, fmaf(cB2, u2a, fmaf(cB3, u3a, fmaf(cB4, u4a, fmaf(cB5, u5a, cB6 * u6a)))));
                             sb = fmaf(cB1, u1b, fmaf(cB2, u2b, fmaf(cB3, u3b, fmaf(cB4, u4b, fmaf(cB5, u5b, cB6 * u6b))))); break;
                }
                float za = fmaf(h, sa, zy0);
                float zb = fmaf(h, sb, zy1);
                if (st == 7) {
                    zy5a = za; zy5b = zb;   // zy of y5 (z-space mirror of y5)
                    float ta = fmaf(cB1, k1a, fmaf(cB2, k2a, fmaf(cB3, k3a, fmaf(cB4, k4a, fmaf(cB5, k5a, cB6 * k6a)))));
                    float tb = fmaf(cB1, k1b, fmaf(cB2, k2b, fmaf(cB3, k3b, fmaf(cB4, k4b, fmaf(cB5, k5b, cB6 * k6b)))));
                    y50 = fmaf(h, ta, ys0);
                    y51 = fmaf(h, tb, ys1);
                }
                float ua, ub, ka, kb;
                do_eval(za, zb, ua, ub, ka, kb);
                switch (st) {
                    case 2: u2a = ua; u2b = ub; k2a = ka; k2b = kb; break;
                    case 3: u3a = ua; u3b = ub; k3a = ka; k3b = kb; break;
                    case 4: u4a = ua; u4b = ub; k4a = ka; k4b = kb; break;
                    case 5: u5a = ua; u5b = ub; k5a = ka; k5b = kb; break;
                    case 6: u6a = ua; u6b = ub; k6a = ka; k6b = kb; break;
                    default: u7a = ua; u7b = ub; k7a = ka; k7b = kb; break;
                }
            }

            // error norm: per-lane 2-dim partial (waves 0-3) -> wave -> LDS -> all
            float rr2 = 0.f;
            if (wave < 4) {
                float es0 = fmaf(cE1, k1a, fmaf(cE2, k2a, fmaf(cE3, k3a,
                            fmaf(cE4, k4a, fmaf(cE5, k5a, fmaf(cE6, k6a, cE7 * k7a))))));
                float es1 = fmaf(cE1, k1b, fmaf(cE2, k2b, fmaf(cE3, k3b,
                            fmaf(cE4, k4b, fmaf(cE5, k5b, fmaf(cE6, k6b, cE7 * k7b))))));
                float err0 = h * es0, err1 = h * es1;
                float sc0 = fmaf(1e-3f, fmaxf(fabsf(ys0), fabsf(y50)), 1e-6f);
                float sc1 = fmaf(1e-3f, fmaxf(fabsf(ys1), fabsf(y51)), 1e-6f);
                float r0 = err0 / sc0, r1 = err1 / sc1;
                rr2 = fmaf(r0, r0, r1 * r1);
            }
            rr2 += __shfl_xor(rr2, 16, 64);   // sum quad bit0
            rr2 += __shfl_xor(rr2, 32, 64);   // sum quad bit1
            rr2 = fold8(rr2);                 // sum esel halves (symmetric, no select)
            if (wave < 4 && lane < 8) rrP[wave * 8 + lane] = rr2;  // lane = elem
            __syncthreads();
            float rs = ((rrP[e] + rrP[8 + e]) + rrP[16 + e]) + rrP[24 + e];
            float en = sqrtf(rs * (1.0f / 64.0f));

            bool accept = (en <= 1.0f) && !done;
            float fac = 0.9f * exp2f(-0.2f * log2f(fmaxf(en, 1e-10f)));
            fac = fminf(fmaxf(fac, 0.2f), 10.0f);

            if (accept) {
                t += dt_c;
                zy0 = zy5a; zy1 = zy5b;       // z-space advance
                u1a = u7a;  u1b = u7b;        // FSAL in u-space
                if (wave < 4) { ys0 = y50; ys1 = y51; k1a = k7a; k1b = k7b; }
            }
            if (!done) dt = dt_c * fac;
            done = done || (t >= t1 - 1e-8f);
            if (__all(done)) break;
        }

        if (wave < 4) {
            float2 yy; yy.x = ys0; yy.y = ys1;
            *(float2*)(out + (elemIdx * NSEG + (seg - 1)) * 64 + j0) = yy;
        }
    }
}

extern "C" void kernel_launch(void* const* d_in, const int* in_sizes, int n_in,
                              void* d_out, int out_size, void* d_ws, size_t ws_size,
                              hipStream_t stream) {
    const float* history = (const float*)d_in[0];
    const float* W1 = (const float*)d_in[1];
    const float* b1 = (const float*)d_in[2];
    const float* W2 = (const float*)d_in[3];
    const float* b2 = (const float*)d_in[4];
    const float* W3 = (const float*)d_in[5];
    const float* b3 = (const float*)d_in[6];
    float* out = (float*)d_out;

    ode_kernel<<<dim3(NB / 8), dim3(512), 0, stream>>>(history, W1, b1, W2, b2, W3, b3, out);
}